// Round 1
// baseline (348.369 us; speedup 1.0000x reference)
//
#include <hip/hip_runtime.h>
#include <hip/hip_bf16.h>

typedef __attribute__((ext_vector_type(8))) short short8;
typedef __attribute__((ext_vector_type(4))) float floatx4;
typedef unsigned short ushort_t;
typedef unsigned int uint_t;

#define HOWO (126 * 126)
#define LDA 40  // padded LDS row stride in elements (80 B: 16B-aligned, 2-way banks = free)

__device__ __forceinline__ ushort_t f2bf(float f) {
    // round-to-nearest-even f32 -> bf16 (inputs are finite, no NaN handling needed)
    uint_t u = __float_as_uint(f);
    u += 0x7fffu + ((u >> 16) & 1u);
    return (ushort_t)(u >> 16);
}

// Each block: 128 consecutive output pixels (m) x all 128 output channels.
// Implicit GEMM: A[m][k] = x[n][ci][ho+kh][wo+kw], B[k][co] = w[co][k] (w layout
// [co][ci*9+kh*3+kw] already matches k-order -> contiguous B staging).
__launch_bounds__(256, 2)
__global__ void conv_min_tanh_kernel(const float* __restrict__ x,
                                     const float* __restrict__ w,
                                     const float* __restrict__ bias,
                                     float* __restrict__ out)
{
    __shared__ ushort_t Atile[128 * LDA];
    __shared__ ushort_t Btile[128 * LDA];
    __shared__ int offs[576];
    __shared__ float red[2][128];

    const int tid = threadIdx.x;
    const int m0  = blockIdx.x * 128;

    // k -> x element offset table (ci*16384 + kh*128 + kw), computed once
    for (int k = tid; k < 576; k += 256) {
        int ci = k / 9;
        int r  = k - ci * 9;
        int kh = r / 3;
        int kw = r - kh * 3;
        offs[k] = ci * 16384 + kh * 128 + kw;
    }

    // staging geometry: thread handles row ml (m for A, co for B), 16 consecutive k
    const int ml   = tid & 127;
    const int half = tid >> 7;

    const int m   = m0 + ml;
    const int n   = m / HOWO;
    const int rem = m - n * HOWO;
    const int ho  = rem / 126;
    const int wo  = rem - ho * 126;
    // &x[n][0][ho][wo]; ho+kh<=127, wo+kw<=127 always in-bounds (VALID conv)
    const float* xb = x + ((size_t)n * 1048576 + ho * 128 + wo);
    const float* wb = w + (size_t)ml * 576;

    floatx4 acc[4][4];
#pragma unroll
    for (int i = 0; i < 4; ++i)
#pragma unroll
        for (int j = 0; j < 4; ++j)
            acc[i][j] = (floatx4){0.f, 0.f, 0.f, 0.f};

    const int lane = tid & 63;
    const int wid  = tid >> 6;
    const int wm   = wid >> 1;   // m-half of the 128x128 tile
    const int wn   = wid & 1;    // co-half
    const int r16  = lane & 15;
    const int quad = lane >> 4;

    __syncthreads();  // offs ready

    for (int it = 0; it < 18; ++it) {
        const int kb = it * 32 + half * 16;

        // global loads first (overlap with previous iter's MFMA; waitcnt before LDS writes)
        float av[16], bv[16];
#pragma unroll
        for (int j = 0; j < 16; ++j)
            av[j] = xb[offs[kb + j]];   // offs read is wave-uniform -> LDS broadcast
        const float* wp = wb + kb;
#pragma unroll
        for (int j = 0; j < 16; ++j)
            bv[j] = wp[j];

        __syncthreads();  // previous iter's fragment reads complete

        short8 pa0, pa1, pb0, pb1;
#pragma unroll
        for (int j = 0; j < 8; ++j) {
            pa0[j] = (short)f2bf(av[j]);
            pa1[j] = (short)f2bf(av[j + 8]);
            pb0[j] = (short)f2bf(bv[j]);
            pb1[j] = (short)f2bf(bv[j + 8]);
        }
        {
            short8* ap = reinterpret_cast<short8*>(&Atile[ml * LDA + half * 16]);
            ap[0] = pa0; ap[1] = pa1;
            short8* bp = reinterpret_cast<short8*>(&Btile[ml * LDA + half * 16]);
            bp[0] = pb0; bp[1] = pb1;
        }
        __syncthreads();  // tiles visible

        short8 af[4], bf8[4];
#pragma unroll
        for (int t4 = 0; t4 < 4; ++t4) {
            af[t4]  = *reinterpret_cast<short8*>(&Atile[(wm * 64 + t4 * 16 + r16) * LDA + quad * 8]);
            bf8[t4] = *reinterpret_cast<short8*>(&Btile[(wn * 64 + t4 * 16 + r16) * LDA + quad * 8]);
        }
#pragma unroll
        for (int tm = 0; tm < 4; ++tm)
#pragma unroll
            for (int tn = 0; tn < 4; ++tn)
                acc[tm][tn] = __builtin_amdgcn_mfma_f32_16x16x32_bf16(
                    af[tm], bf8[tn], acc[tm][tn], 0, 0, 0);
    }

    // epilogue: +bias, min over co, tanh(tanh(.))
    float bvv[4];
#pragma unroll
    for (int tn = 0; tn < 4; ++tn)
        bvv[tn] = bias[wn * 64 + tn * 16 + r16];

#pragma unroll
    for (int tm = 0; tm < 4; ++tm) {
#pragma unroll
        for (int r = 0; r < 4; ++r) {
            // C/D layout: row(m) = quad*4 + r, col(co) = r16
            float v = acc[tm][0][r] + bvv[0];
            v = fminf(v, acc[tm][1][r] + bvv[1]);
            v = fminf(v, acc[tm][2][r] + bvv[2]);
            v = fminf(v, acc[tm][3][r] + bvv[3]);
            // butterfly min across the 16 col-lanes (lane bits 0-3)
            v = fminf(v, __shfl_xor(v, 1, 64));
            v = fminf(v, __shfl_xor(v, 2, 64));
            v = fminf(v, __shfl_xor(v, 4, 64));
            v = fminf(v, __shfl_xor(v, 8, 64));
            if (r16 == 0)
                red[wn][wm * 64 + tm * 16 + quad * 4 + r] = v;
        }
    }
    __syncthreads();

    if (tid < 128) {
        float v = fminf(red[0][tid], red[1][tid]);
        v = tanhf(tanhf(v));
        out[m0 + tid] = v;  // out is [32,1,126,126] contiguous == m order
    }
}

extern "C" void kernel_launch(void* const* d_in, const int* in_sizes, int n_in,
                              void* d_out, int out_size, void* d_ws, size_t ws_size,
                              hipStream_t stream) {
    const float* x    = (const float*)d_in[0];   // [32,64,128,128] f32
    const float* w    = (const float*)d_in[1];   // [128,64,3,3] f32
    const float* bias = (const float*)d_in[2];   // [128] f32
    float* out = (float*)d_out;                  // [32,1,126,126] f32

    // 508032 pixels / 128 per block = 3969 blocks exactly (no tail)
    conv_min_tanh_kernel<<<dim3(3969), dim3(256), 0, stream>>>(x, w, bias, out);
}